// Round 3
// baseline (12006.006 us; speedup 1.0000x reference)
//
#include <hip/hip_runtime.h>
#include <hip/hip_fp16.h>
#include <math.h>

#define SEQ 512
#define ETA 0.1f
#define KAPPA 0.05f
#define AA 0.85f   /* 1 - ETA - KAPPA */

typedef _Float16 f16x8 __attribute__((ext_vector_type(8)));
typedef float f32x4 __attribute__((ext_vector_type(4)));

// workspace layout (float offsets)
#define WS_G    ((size_t)0)        /* 65536  G = B*B^T               */
#define WS_GD   ((size_t)65536)    /* 256    diag(G)                 */
#define WS_M0   ((size_t)65792)    /* 256    m0 = mean bubbles       */
#define WS_BX   ((size_t)66048)    /* 512*256 B*x_t                  */
#define WS_X2   ((size_t)197120)   /* 512    ||x_t||^2               */
#define WS_ZS   ((size_t)197632)   /* 512*256 d*Z                    */
#define WS_YS   ((size_t)328704)   /* 512*256 x + d*y                */
#define WS_GS   ((size_t)459776)   /* 4*512*256 g_1..g_4             */
#define WS_HS   ((size_t)984064)   /* 4*512   h_1..h_4               */
#define WS_ALS  ((size_t)986112)   /* 512*256 alpha_5                */
#define WS_BETS ((size_t)1117184)  /* 5*512*256 beta_5               */
#define WS_CT   ((size_t)1772544)  /* 512*5*256 c_0..c_4             */

__device__ __forceinline__ float wred_sum(float v) {
#pragma unroll
  for (int m = 1; m < 64; m <<= 1) v += __shfl_xor(v, m, 64);
  return v;
}
__device__ __forceinline__ float wred_min(float v) {
#pragma unroll
  for (int m = 1; m < 64; m <<= 1) v = fminf(v, __shfl_xor(v, m, 64));
  return v;
}
__device__ __forceinline__ float wred_max(float v) {
#pragma unroll
  for (int m = 1; m < 64; m <<= 1) v = fmaxf(v, __shfl_xor(v, m, 64));
  return v;
}
__device__ __forceinline__ float rfl(float x) {
  return __builtin_bit_cast(float, __builtin_amdgcn_readfirstlane(__builtin_bit_cast(int, x)));
}

// ---------------- K0a: G = B B^T, Gd ----------------
__global__ void k0_gram(const float* __restrict__ B, float* __restrict__ ws) {
  float* G = ws + WS_G;
  float* Gd = ws + WS_GD;
  __shared__ float bi[256];
  const int i = blockIdx.x, j = threadIdx.x;
  bi[j] = B[(size_t)i * 256 + j];
  __syncthreads();
  float a0 = 0.f, a1 = 0.f, a2 = 0.f, a3 = 0.f;
#pragma unroll
  for (int c = 0; c < 256; c += 4) {
    float4 b4 = *(const float4*)&B[(size_t)j * 256 + c];
    a0 = fmaf(bi[c + 0], b4.x, a0);
    a1 = fmaf(bi[c + 1], b4.y, a1);
    a2 = fmaf(bi[c + 2], b4.z, a2);
    a3 = fmaf(bi[c + 3], b4.w, a3);
  }
  float acc = (a0 + a1) + (a2 + a3);
  G[(size_t)i * 256 + j] = acc;
  if (i == j) Gd[i] = acc;
}

// ---------------- K0c: m0 ----------------
__global__ void k0_m0(const float* __restrict__ B, float* __restrict__ ws) {
  float* M0 = ws + WS_M0;
  const int d = threadIdx.x;
  float acc = 0.f;
  for (int i = 0; i < 256; ++i) acc += B[(size_t)i * 256 + d];
  M0[d] = acc * (1.0f / 256.0f);
}

// ---------------- K0b: BX[t] = B x_t, X2[t] ----------------
__global__ void k0_bx(const float* __restrict__ B, const float* __restrict__ embed,
                      const int* __restrict__ toks, float* __restrict__ ws) {
  float* BX = ws + WS_BX;
  float* X2 = ws + WS_X2;
  __shared__ float xs[256];
  __shared__ float red[4];
  const int t = blockIdx.x, i = threadIdx.x;
  const int lane = i & 63, wid = i >> 6;
  const int tok = toks[t];
  float xv = embed[(size_t)tok * 256 + i];
  xs[i] = xv;
  float p = wred_sum(xv * xv);
  if (lane == 0) red[wid] = p;
  __syncthreads();
  if (i == 0) X2[t] = red[0] + red[1] + red[2] + red[3];
  float a0 = 0.f, a1 = 0.f, a2 = 0.f, a3 = 0.f;
#pragma unroll
  for (int c = 0; c < 256; c += 4) {
    float4 b4 = *(const float4*)&B[(size_t)i * 256 + c];
    a0 = fmaf(xs[c + 0], b4.x, a0);
    a1 = fmaf(xs[c + 1], b4.y, a1);
    a2 = fmaf(xs[c + 2], b4.z, a2);
    a3 = fmaf(xs[c + 3], b4.w, a3);
  }
  BX[(size_t)t * 256 + i] = (a0 + a1) + (a2 + a3);
}

// ---------------- K1: sequential scan ----------------
// 1024 threads: i = tid>>2 (row/dim), h = tid&3 (quarter of G-row).
// Gq[16] float4 = 64 VGPRs/thread, total ~105 VGPR -> no scratch spill at the
// 128-VGPR cap (16 waves/CU). Per round-pair: 2 barriers; matvec input alpha_k
// is written one segment ahead (G*g_k rebuilt by linearity from G*alpha_k and
// register history G*g_l). Reductions: 16-lane h-group shuffles + LDS f32
// atomics into ping-ponged 8-float buffers.
__global__ __launch_bounds__(1024, 1) void k1_seq(
    const float* __restrict__ embed, const int* __restrict__ toks,
    const float* __restrict__ mdbp, const float* __restrict__ sensp,
    float* __restrict__ ws) {
  const int tid = threadIdx.x;
  const int lane = tid & 63;
  const int i = tid >> 2, h = tid & 3;
  const float* G = ws + WS_G;
  const float* Gd = ws + WS_GD;
  const float* BX = ws + WS_BX;
  const float* X2 = ws + WS_X2;
  float* ZS = ws + WS_ZS;
  float* YS = ws + WS_YS;
  float* GS = ws + WS_GS;
  float* HS = ws + WS_HS;
  float* ALS = ws + WS_ALS;
  float* BETS = ws + WS_BETS;

  __shared__ __align__(16) float gcur[4 * 68];  // padded: quarter q at q*68
  __shared__ float dresb[2][8];
  __shared__ float bbarb[2][8];

  // quarter G-row in VGPRs
  float4 Gq[16];
  {
    const float4* gp = (const float4*)(G + (size_t)i * 256 + (size_t)h * 64);
#pragma unroll
    for (int j = 0; j < 16; ++j) Gq[j] = gp[j];
  }
  const float Gdi = Gd[i];
  const float mdb = rfl(mdbp[0]);
  const float sens = fabsf(rfl(sensp[0]));

  // q0 = G * (1/256) is constant across t
  float q0i;
  {
    float s = 0.f;
#pragma unroll
    for (int j = 0; j < 16; ++j) s += (Gq[j].x + Gq[j].y) + (Gq[j].z + Gq[j].w);
    s += __shfl_xor(s, 1, 64);
    s += __shfl_xor(s, 2, 64);
    q0i = s * (1.0f / 256.0f);
  }

  float x_c = embed[(size_t)toks[0] * 256 + i];
  float bx_c = BX[i];
  float x2_c = rfl(X2[0]);

  // zero all reduction buffers
  if (tid < 16) dresb[tid >> 3][tid & 7] = 0.f;
  else if (tid < 32) bbarb[(tid - 16) >> 3][tid & 7] = 0.f;
  __syncthreads();
  // preamble reductions: c00 = mean(q0), mbx = mean(BX[0])
  {
    float mv0 = 0.f;
    if (h == 0) mv0 = q0i * (1.0f / 256.0f);
    else if (h == 1) mv0 = bx_c * (1.0f / 256.0f);
#pragma unroll
    for (int m = 4; m <= 32; m <<= 1) mv0 += __shfl_xor(mv0, m, 64);
    if (lane < 2) atomicAdd(&dresb[0][lane], mv0);
  }
  __syncthreads();
  const float c00 = rfl(dresb[0][0]);
  float mbx = rfl(dresb[0][1]);

  float Zi = 0.f, yi = 0.f, wi = 0.f;
  float mm2 = 0.f, mw = 0.f, dotxm = 0.f;

  // t = 0 step scalars (mem == 0 -> nov = 1)
  float dec = 1.0f / (1.0f + expf(-(mdb - sens)));
  float od = 1.0f - dec;
  float ri = bx_c;
  float XM2 = x2_c;
  float mean_r = mbx;
  if (h == 0) ZS[i] = 0.f;
  else if (h == 1) YS[i] = x_c;

  float gh[6], Ggh[6], hhv[6], bmat[5], xmm[5], alpha;
  gh[0] = 1.0f / 256.0f; Ggh[0] = q0i; hhv[0] = 0.f;
  // round-0 epilogue for t = 0
  {
    const float xmm0 = mean_r;
    const float tki = ETA * ri + KAPPA * q0i;
    const float CC00 = (ETA * ETA) * XM2 + 2.f * (ETA * KAPPA) * xmm0 +
                       (KAPPA * KAPPA) * c00;
    const float n2 = fmaxf(AA * AA * Gdi + 2.f * AA * tki + CC00, 0.f);
    const float inv = 1.0f / (sqrtf(n2) + 1e-10f);
    bmat[0] = inv; alpha = AA * inv; xmm[0] = xmm0;
  }
  if (h == 0) gcur[(i >> 6) * 68 + (i & 63)] = alpha;
  {
    float bv0 = (h == 0) ? bmat[0] : 0.f;
#pragma unroll
    for (int m = 4; m <= 32; m <<= 1) bv0 += __shfl_xor(bv0, m, 64);
    if (lane == 0) atomicAdd(&bbarb[1][0], bv0);
  }
  __syncthreads();
  int pq = 1;

#pragma unroll 1
  for (int t = 0; t < SEQ; ++t) {
    const int tn = (t + 1 < SEQ) ? (t + 1) : t;
    const int tokn = toks[tn];
    const float x_n = embed[(size_t)tokn * 256 + i];
    const float bx_n = BX[(size_t)tn * 256 + i];
    const float x2_n = rfl(X2[tn]);
    float q5sav = 0.f;

#pragma unroll
    for (int k = 1; k <= 5; ++k) {
      // ===================== A_k =====================
      if (tid < 8) dresb[1 - pq][tid] = 0.f;
      else if (tid < 16) bbarb[1 - pq][tid - 8] = 0.f;
      // matvec M[i] = sum_j G[i][j] * alpha_k[j]
      float4 av = {0.f, 0.f, 0.f, 0.f};
      const float4* gc4 = (const float4*)&gcur[h * 68];
#pragma unroll
      for (int j = 0; j < 16; ++j) {
        const float4 g4 = gc4[j];
        av.x = fmaf(Gq[j].x, g4.x, av.x);
        av.y = fmaf(Gq[j].y, g4.y, av.y);
        av.z = fmaf(Gq[j].z, g4.z, av.z);
        av.w = fmaf(Gq[j].w, g4.w, av.w);
      }
      float M = (av.x + av.y) + (av.z + av.w);
      M += __shfl_xor(M, 1, 64);
      M += __shfl_xor(M, 2, 64);
      // g_k, Gg_k, h_k from bbar history
      float hk = 0.f, gk = alpha * (1.0f / 256.0f), Ggk = M * (1.0f / 256.0f);
#pragma unroll
      for (int l = 0; l < 5; ++l)
        if (l < k) {
          const float bb = rfl(bbarb[pq][l]) * (1.0f / 256.0f);
          hk += bb * (ETA + KAPPA * hhv[l]);
          gk = fmaf(KAPPA * bb, gh[l], gk);
          Ggk = fmaf(KAPPA * bb, Ggh[l], Ggk);
        }
      const float qk = Ggk + hk * ri;
      gh[k] = gk; Ggh[k] = Ggk; hhv[k] = hk;
      if (k <= 4) {
        if (h == 2) GS[(size_t)(k - 1) * (SEQ * 256) + (size_t)t * 256 + i] = gk;
        if (tid == 0) HS[(size_t)(k - 1) * SEQ + t] = hk;
      }
      // reduction vectors (h-group l&3, slots l and l+4)
      float vv[8];
      if (k < 5) {
#pragma unroll
        for (int l = 0; l < 8; ++l) {
          if (l <= k) vv[l] = gk * (Ggh[l] + hhv[l] * ri);
          else if (l == k + 1) vv[l] = ri * gk;
          else vv[l] = 0.f;
        }
      } else {
        q5sav = qk;
        vv[0] = gk * qk;                  // <g5,q5>
        vv[1] = ri * gk;                  // <r,g5>
        vv[2] = wi * gk;                  // <w,g5>
        vv[3] = qk * (1.0f / 256.0f);     // mean(q5)
        vv[4] = bx_n * Zi + x_n * yi;     // <x_n, mem_old>
        vv[5] = bx_n * gk;                // <bx_n, g5>
        vv[6] = x_n * x_c;                // <x_n, x_c>
        vv[7] = bx_n * (1.0f / 256.0f);   // mean(bx_n)
      }
      float mv0 = (h == 0) ? vv[0] : (h == 1) ? vv[1] : (h == 2) ? vv[2] : vv[3];
      float mv1 = (h == 0) ? vv[4] : (h == 1) ? vv[5] : (h == 2) ? vv[6] : vv[7];
#pragma unroll
      for (int m = 4; m <= 32; m <<= 1) {
        mv0 += __shfl_xor(mv0, m, 64);
        mv1 += __shfl_xor(mv1, m, 64);
      }
      const int nv = (k < 5) ? (k + 2) : 8;
      if (lane < 8 && lane < nv) atomicAdd(&dresb[pq][lane], lane < 4 ? mv0 : mv1);
      __syncthreads();

      // ===================== B_k =====================
      if (k < 5) {
        float dres[7];
#pragma unroll
        for (int l = 0; l < 7; ++l)
          if (l <= k + 1) dres[l] = rfl(dresb[pq][l]);
        const float xmmk = dres[k + 1] + hk * XM2;
        const float tki = ETA * ri + KAPPA * qk;
        float sc = alpha * tki;
#pragma unroll
        for (int jj = 0; jj < 4; ++jj)
          if (jj < k) {
            const float MMjk = dres[jj] + hk * xmm[jj];
            const float CCjk = (ETA * ETA) * XM2 + (ETA * KAPPA) * (xmm[jj] + xmmk) +
                               (KAPPA * KAPPA) * MMjk;
            sc = fmaf(bmat[jj], CCjk, sc);
          }
        const float MMkk = dres[k] + hk * xmmk;
        const float CCkk = (ETA * ETA) * XM2 + 2.f * (ETA * KAPPA) * xmmk +
                           (KAPPA * KAPPA) * MMkk;
        const float n2 = fmaxf(AA * AA + 2.f * AA * sc + CCkk, 0.f);
        const float inv = 1.0f / (sqrtf(n2) + 1e-10f);
#pragma unroll
        for (int jj = 0; jj < 4; ++jj)
          if (jj < k) bmat[jj] *= AA * inv;
        bmat[k] = inv;
        alpha *= AA * inv;
        xmm[k] = xmmk;
        if (k == 4) {
          if (h == 3) ALS[(size_t)t * 256 + i] = alpha;
          if (h == 0) {
            BETS[(size_t)0 * (SEQ * 256) + (size_t)t * 256 + i] = bmat[0];
            BETS[(size_t)4 * (SEQ * 256) + (size_t)t * 256 + i] = bmat[4];
          } else if (h == 1) {
            BETS[(size_t)1 * (SEQ * 256) + (size_t)t * 256 + i] = bmat[1];
          } else if (h == 2) {
            BETS[(size_t)2 * (SEQ * 256) + (size_t)t * 256 + i] = bmat[2];
          } else {
            BETS[(size_t)3 * (SEQ * 256) + (size_t)t * 256 + i] = bmat[3];
          }
        }
        if (h == 0) gcur[(i >> 6) * 68 + (i & 63)] = alpha;  // alpha_{k+1}
        float bv0 = (h == 0) ? bmat[0]
                  : (h == 1) ? ((k >= 1) ? bmat[1] : 0.f)
                  : (h == 2) ? ((k >= 2) ? bmat[2] : 0.f)
                             : ((k >= 3) ? bmat[3] : 0.f);
        float bv1 = (h == 0 && k >= 4) ? bmat[4] : 0.f;
#pragma unroll
        for (int m = 4; m <= 32; m <<= 1) {
          bv0 += __shfl_xor(bv0, m, 64);
          bv1 += __shfl_xor(bv1, m, 64);
        }
        if (lane < 8 && lane <= k)
          atomicAdd(&bbarb[1 - pq][lane], lane < 4 ? bv0 : bv1);
        __syncthreads();
        pq ^= 1;
      } else {
        // B_5: memory update + next-step scalars + next round-0
        float dr[8];
#pragma unroll
        for (int l = 0; l < 8; ++l) dr[l] = rfl(dresb[pq][l]);
        const float h5 = hhv[5];
        const float g5 = gh[5];
        const float q5 = q5sav;
        const float xmm5 = dr[1] + h5 * XM2;
        const float m52 = dr[0] + h5 * xmm5;
        const float cmm5 = dr[2] + h5 * (dotxm + dec * mm2);
        const float lamc = dec * (1.0f + od * h5);
        Zi = lamc * Zi + od * g5;
        yi = lamc * yi + od * h5 * x_c;
        wi = dec * wi + od * q5;
        mm2 = fmaxf(dec * dec * mm2 + 2.f * dec * od * cmm5 + od * od * m52, 0.f);
        mw = dec * mw + od * dr[3];
        dotxm = lamc * dr[4] + od * (dr[5] + h5 * dr[6]);
        mbx = dr[7];
        x_c = x_n; bx_c = bx_n; x2_c = x2_n;
        // next-step scalars
        const float memnorm = sqrtf(mm2) + 1e-10f;
        const float xnorm = sqrtf(x2_c) + 1e-10f;
        const float nov = (memnorm > 1e-8f) ? (1.0f - dotxm / (xnorm * memnorm)) : 1.0f;
        dec = 1.0f / (1.0f + expf(-(mdb - sens * nov)));
        od = 1.0f - dec;
        ri = bx_c + dec * wi;
        XM2 = x2_c + 2.f * dec * dotxm + dec * dec * mm2;
        mean_r = mbx + dec * mw;
        if (t + 1 < SEQ) {
          if (h == 0) ZS[(size_t)(t + 1) * 256 + i] = dec * Zi;
          else if (h == 1) YS[(size_t)(t + 1) * 256 + i] = x_c + dec * yi;
        }
        // round-0 epilogue for next step
        const float xmm0 = mean_r;
        const float tki = ETA * ri + KAPPA * q0i;
        const float CC00 = (ETA * ETA) * XM2 + 2.f * (ETA * KAPPA) * xmm0 +
                           (KAPPA * KAPPA) * c00;
        const float n2 = fmaxf(AA * AA * Gdi + 2.f * AA * tki + CC00, 0.f);
        const float inv = 1.0f / (sqrtf(n2) + 1e-10f);
        bmat[0] = inv; alpha = AA * inv; xmm[0] = xmm0;
        if (h == 0) gcur[(i >> 6) * 68 + (i & 63)] = alpha;  // alpha_1
        float bv0 = (h == 0) ? bmat[0] : 0.f;
#pragma unroll
        for (int m = 4; m <= 32; m <<= 1) bv0 += __shfl_xor(bv0, m, 64);
        if (lane == 0) atomicAdd(&bbarb[1 - pq][0], bv0);
        __syncthreads();
        pq ^= 1;
      }
    }
  }
}

// ---------------- K15: materialize xm and c_0..c_4 per step ----------------
__global__ void k15_cvec(const float* __restrict__ B, float* __restrict__ ws) {
  const float* ZS = ws + WS_ZS;
  const float* YS = ws + WS_YS;
  const float* GS = ws + WS_GS;
  const float* HS = ws + WS_HS;
  const float* M0 = ws + WS_M0;
  float* CT = ws + WS_CT;
  const int t = blockIdx.x, d = threadIdx.x;
  __shared__ float zs[256], g1[256], g2[256], g3[256], g4[256];
  zs[d] = ZS[(size_t)t * 256 + d];
  g1[d] = GS[0 * (SEQ * 256) + (size_t)t * 256 + d];
  g2[d] = GS[1 * (SEQ * 256) + (size_t)t * 256 + d];
  g3[d] = GS[2 * (SEQ * 256) + (size_t)t * 256 + d];
  g4[d] = GS[3 * (SEQ * 256) + (size_t)t * 256 + d];
  __syncthreads();
  float xa = 0.f, b1 = 0.f, b2 = 0.f, b3 = 0.f, b4 = 0.f;
  for (int ii = 0; ii < 256; ++ii) {
    const float Bv = B[(size_t)ii * 256 + d];
    xa = fmaf(zs[ii], Bv, xa);
    b1 = fmaf(g1[ii], Bv, b1);
    b2 = fmaf(g2[ii], Bv, b2);
    b3 = fmaf(g3[ii], Bv, b3);
    b4 = fmaf(g4[ii], Bv, b4);
  }
  const float xm = YS[(size_t)t * 256 + d] + xa;
  float* ctt = CT + (size_t)t * 1280;
  ctt[0 * 256 + d] = ETA * xm + KAPPA * M0[d];
  const float h1 = HS[0 * SEQ + t], h2 = HS[1 * SEQ + t];
  const float h3 = HS[2 * SEQ + t], h4 = HS[3 * SEQ + t];
  ctt[1 * 256 + d] = (ETA + KAPPA * h1) * xm + KAPPA * b1;
  ctt[2 * 256 + d] = (ETA + KAPPA * h2) * xm + KAPPA * b2;
  ctt[3 * 256 + d] = (ETA + KAPPA * h3) * xm + KAPPA * b3;
  ctt[4 * 256 + d] = (ETA + KAPPA * h4) * xm + KAPPA * b4;
}

// ---------------- K2: per-step rho -> eigenvalues ----------------
__global__ __launch_bounds__(1024, 4) void k2_eig(
    const float* __restrict__ B, const float* __restrict__ ws,
    float* __restrict__ out) {
  const int t = blockIdx.x;
  const int tid = threadIdx.x;
  const int lane = tid & 63, wid = tid >> 6;
  const float* CT = ws + WS_CT + (size_t)t * 1280;
  const float* ALS = ws + WS_ALS + (size_t)t * 256;
  const float* BETS = ws + WS_BETS;

  __shared__ __align__(16) unsigned char bigbuf[135168];  // sT fp16 [256][264] / packed rho fp32
  _Float16* sT = (_Float16*)bigbuf;
  float* pk = (float*)bigbuf;
  __shared__ __align__(16) float ct[1280];
  __shared__ float vx[256], pv[256], qv[256];
  __shared__ float dd[256], ee[256], e2[256], lamv[256];
  __shared__ float red[16];

  for (int idx = tid; idx < 1280; idx += 1024) ct[idx] = CT[idx];
  __syncthreads();

  // --- regenerate s5 rows, store transposed fp16 ---
  {
    const int r = tid >> 2, q = tid & 3;
    const float al = ALS[r];
    const float be0 = BETS[(size_t)0 * (SEQ * 256) + (size_t)t * 256 + r];
    const float be1 = BETS[(size_t)1 * (SEQ * 256) + (size_t)t * 256 + r];
    const float be2 = BETS[(size_t)2 * (SEQ * 256) + (size_t)t * 256 + r];
    const float be3 = BETS[(size_t)3 * (SEQ * 256) + (size_t)t * 256 + r];
    const float be4 = BETS[(size_t)4 * (SEQ * 256) + (size_t)t * 256 + r];
#pragma unroll
    for (int j4 = 0; j4 < 16; ++j4) {
      const int d0 = q * 64 + j4 * 4;
      const float4 Bv = *(const float4*)&B[(size_t)r * 256 + d0];
      const float4 c0 = *(const float4*)&ct[0 * 256 + d0];
      const float4 c1 = *(const float4*)&ct[1 * 256 + d0];
      const float4 c2 = *(const float4*)&ct[2 * 256 + d0];
      const float4 c3 = *(const float4*)&ct[3 * 256 + d0];
      const float4 c4 = *(const float4*)&ct[4 * 256 + d0];
      const float s0 = al * Bv.x + be0 * c0.x + be1 * c1.x + be2 * c2.x + be3 * c3.x + be4 * c4.x;
      const float s1 = al * Bv.y + be0 * c0.y + be1 * c1.y + be2 * c2.y + be3 * c3.y + be4 * c4.y;
      const float s2 = al * Bv.z + be0 * c0.z + be1 * c1.z + be2 * c2.z + be3 * c3.z + be4 * c4.z;
      const float s3 = al * Bv.w + be0 * c0.w + be1 * c1.w + be2 * c2.w + be3 * c3.w + be4 * c4.w;
      sT[(size_t)(d0 + 0) * 264 + r] = (_Float16)s0;
      sT[(size_t)(d0 + 1) * 264 + r] = (_Float16)s1;
      sT[(size_t)(d0 + 2) * 264 + r] = (_Float16)s2;
      sT[(size_t)(d0 + 3) * 264 + r] = (_Float16)s3;
    }
  }
  __syncthreads();

  // --- rho = sT * sT^T / 256 via MFMA f16 (4x4 tiles of 16x16 per wave) ---
  f32x4 acc[4][4];
#pragma unroll
  for (int ti = 0; ti < 4; ++ti)
#pragma unroll
    for (int tj = 0; tj < 4; ++tj) {
      f32x4 z = {0.f, 0.f, 0.f, 0.f};
      acc[ti][tj] = z;
    }
  {
    const int Ib = (wid >> 2) * 4, Jb = (wid & 3) * 4;
    const int mr = lane & 15, kg = lane >> 4;
#pragma unroll 1
    for (int kb = 0; kb < 8; ++kb) {
      const int ko = kb * 32 + kg * 8;
      f16x8 aF[4], bF[4];
#pragma unroll
      for (int ti = 0; ti < 4; ++ti)
        aF[ti] = *(const f16x8*)&sT[(size_t)((Ib + ti) * 16 + mr) * 264 + ko];
#pragma unroll
      for (int tj = 0; tj < 4; ++tj)
        bF[tj] = *(const f16x8*)&sT[(size_t)((Jb + tj) * 16 + mr) * 264 + ko];
#pragma unroll
      for (int ti = 0; ti < 4; ++ti)
#pragma unroll
        for (int tj = 0; tj < 4; ++tj)
          acc[ti][tj] = __builtin_amdgcn_mfma_f32_16x16x32_f16(aF[ti], bF[tj], acc[ti][tj], 0, 0, 0);
    }
  }
  __syncthreads();
  {
    const int Ib = (wid >> 2) * 4, Jb = (wid & 3) * 4;
    const int cn = lane & 15, rg = lane >> 4;
#pragma unroll
    for (int ti = 0; ti < 4; ++ti)
#pragma unroll
      for (int tj = 0; tj < 4; ++tj) {
        const int C = (Jb + tj) * 16 + cn;
        const int Rb = (Ib + ti) * 16 + rg * 4;
#pragma unroll
        for (int rr = 0; rr < 4; ++rr) {
          const int R = Rb + rr;
          if (R >= C) pk[R * (R + 1) / 2 + C] = acc[ti][tj][rr] * (1.0f / 256.0f);
        }
      }
  }
  __syncthreads();

  // --- Householder tridiagonalization on packed lower fp32 ---
#pragma unroll 1
  for (int j = 0; j < 254; ++j) {
    const int m = 255 - j;
    const float x0 = pk[(j + 1) * (j + 2) / 2 + j];
    float ps = 0.f;
    if (tid < m) {
      const int gr = j + 1 + tid;
      const float xv_ = pk[gr * (gr + 1) / 2 + j];
      vx[tid] = xv_;
      ps = xv_ * xv_;
    }
    ps = wred_sum(ps);
    if (lane == 0) red[wid] = ps;
    __syncthreads();  // T1
    float sig2 = 0.f;
#pragma unroll
    for (int w = 0; w < 16; ++w) sig2 += red[w];
    const float sig = sqrtf(sig2);
    const float sg = (x0 >= 0.f) ? 1.f : -1.f;
    const bool live = (sig2 > 1e-26f);
    const float beta = live ? (1.0f / (sig * (sig + fabsf(x0)))) : 0.f;
    const float v0 = live ? (x0 + sg * sig) : 0.f;
    if (tid == 0) {
      dd[j] = pk[j * (j + 1) / 2 + j];
      ee[j] = live ? (-sg * sig) : x0;
      vx[0] = v0;
    }
    __syncthreads();  // T2
    {
      const int ri_ = tid >> 2, qd = tid & 3;
      float acc2 = 0.f;
      if (ri_ < m) {
        const int gr = j + 1 + ri_;
        const int c0 = (m * qd) >> 2, c1 = (m * (qd + 1)) >> 2;
        const int rowbase = gr * (gr + 1) / 2 + (j + 1);
        const int clend = min(c1, ri_ + 1);
        for (int c = c0; c < clend; ++c) acc2 = fmaf(pk[rowbase + c], vx[c], acc2);
        const int cu = max(c0, ri_ + 1);
        if (cu < c1) {
          int gc = j + 1 + cu;
          int ub = gc * (gc + 1) / 2 + gr;
          int stp = gc + 1;
          for (int c = cu; c < c1; ++c) { acc2 = fmaf(pk[ub], vx[c], acc2); ub += stp; ++stp; }
        }
      }
      acc2 += __shfl_xor(acc2, 1, 64);
      acc2 += __shfl_xor(acc2, 2, 64);
      float vpp = 0.f;
      if ((tid & 3) == 0 && (tid >> 2) < m) { pv[tid >> 2] = acc2; vpp = acc2 * vx[tid >> 2]; }
      vpp = wred_sum(vpp);
      if (lane == 0) red[wid] = vpp;
    }
    __syncthreads();  // T3
    float vtp = 0.f;
#pragma unroll
    for (int w = 0; w < 16; ++w) vtp += red[w];
    const float gamma = 0.5f * beta * beta * vtp;
    if (tid < m) qv[tid] = beta * pv[tid] - gamma * vx[tid];
    __syncthreads();  // T4
    {
      const int Q = tid >> 2, qd = tid & 3;
      const int i2 = m - 1 - Q;
      if (Q <= i2 && Q < m) {
        {
          const int gr = j + 1 + Q;
          const int rb = gr * (gr + 1) / 2 + (j + 1);
          const float vi = vx[Q], qi = qv[Q];
          const int cs = (qd * (Q + 1)) >> 2, ce = ((qd + 1) * (Q + 1)) >> 2;
          for (int c = cs; c < ce; ++c) pk[rb + c] -= vi * qv[c] + qi * vx[c];
        }
        if (i2 > Q) {
          const int gr = j + 1 + i2;
          const int rb = gr * (gr + 1) / 2 + (j + 1);
          const float vi = vx[i2], qi = qv[i2];
          const int cs = (qd * (i2 + 1)) >> 2, ce = ((qd + 1) * (i2 + 1)) >> 2;
          for (int c = cs; c < ce; ++c) pk[rb + c] -= vi * qv[c] + qi * vx[c];
        }
      }
    }
    __syncthreads();  // T5
  }
  if (tid == 0) {
    dd[254] = pk[254 * 255 / 2 + 254];
    dd[255] = pk[255 * 256 / 2 + 255];
    ee[254] = pk[255 * 256 / 2 + 254];
    ee[255] = 0.f;
  }
  __syncthreads();
  if (tid < 256) e2[tid] = ee[tid] * ee[tid];
  __syncthreads();
  float glo = 1e30f, ghi = -1e30f;
  if (tid < 256) {
    const float rad = fabsf(ee[tid]) + ((tid > 0) ? fabsf(ee[tid - 1]) : 0.f);
    glo = dd[tid] - rad;
    ghi = dd[tid] + rad;
  }
  {
    float v = wred_min(glo);
    if (lane == 0) red[wid] = v;
    __syncthreads();
    float lo0 = 1e30f;
#pragma unroll
    for (int w = 0; w < 16; ++w) lo0 = fminf(lo0, red[w]);
    __syncthreads();
    v = wred_max(ghi);
    if (lane == 0) red[wid] = v;
    __syncthreads();
    float hi0 = -1e30f;
#pragma unroll
    for (int w = 0; w < 16; ++w) hi0 = fmaxf(hi0, red[w]);
    lo0 -= 1e-3f + 1e-3f * fabsf(lo0);
    hi0 += 1e-3f + 1e-3f * fabsf(hi0);
    if (tid < 256) {
      float lo = lo0, hi = hi0;
      for (int it = 0; it < 21; ++it) {
        const float x = 0.5f * (lo + hi);
        int cnt = 0;
        float qq = dd[0] - x;
        cnt += (qq < 0.f);
        for (int ii = 1; ii < 256; ++ii) {
          float dn = qq;
          if (fabsf(dn) < 1e-25f) dn = (dn < 0.f) ? -1e-25f : 1e-25f;
          qq = (dd[ii] - x) - e2[ii - 1] * __builtin_amdgcn_rcpf(dn);
          cnt += (qq < 0.f);
        }
        if (cnt >= tid + 1) hi = x; else lo = x;
      }
      lamv[tid] = fmaxf(0.5f * (lo + hi), 0.f);
    }
  }
  __syncthreads();
  float sv = (tid < 256) ? lamv[tid] : 0.f;
  sv = wred_sum(sv);
  if (lane == 0) red[wid] = sv;
  __syncthreads();
  float S = 0.f;
#pragma unroll
  for (int w = 0; w < 16; ++w) S += red[w];
  if (tid < 256) out[(size_t)t * 256 + tid] = lamv[tid] / (S + 1e-10f);
}

extern "C" void kernel_launch(void* const* d_in, const int* in_sizes, int n_in,
                              void* d_out, int out_size, void* d_ws, size_t ws_size,
                              hipStream_t stream) {
  const float* embed = (const float*)d_in[0];
  const float* B = (const float*)d_in[1];
  const float* mdb = (const float*)d_in[2];
  const float* sens = (const float*)d_in[3];
  const int* toks = (const int*)d_in[4];
  float* out = (float*)d_out;
  float* ws = (float*)d_ws;

  k0_gram<<<dim3(256), dim3(256), 0, stream>>>(B, ws);
  k0_m0<<<dim3(1), dim3(256), 0, stream>>>(B, ws);
  k0_bx<<<dim3(SEQ), dim3(256), 0, stream>>>(B, embed, toks, ws);
  k1_seq<<<dim3(1), dim3(1024), 0, stream>>>(embed, toks, mdb, sens, ws);
  k15_cvec<<<dim3(SEQ), dim3(256), 0, stream>>>(B, ws);
  k2_eig<<<dim3(SEQ), dim3(1024), 0, stream>>>(B, ws, out);
}

// Round 4
// 10625.636 us; speedup vs baseline: 1.1299x; 1.1299x over previous
//
#include <hip/hip_runtime.h>
#include <hip/hip_fp16.h>
#include <math.h>

#define SEQ 512
#define ETA 0.1f
#define KAPPA 0.05f
#define AA 0.85f   /* 1 - ETA - KAPPA */

typedef _Float16 f16x8 __attribute__((ext_vector_type(8)));
typedef float f32x4 __attribute__((ext_vector_type(4)));

// workspace layout (float offsets)
#define WS_G    ((size_t)0)        /* 65536  G = B*B^T               */
#define WS_GD   ((size_t)65536)    /* 256    diag(G)                 */
#define WS_M0   ((size_t)65792)    /* 256    m0 = mean bubbles       */
#define WS_BX   ((size_t)66048)    /* 512*256 B*x_t                  */
#define WS_X2   ((size_t)197120)   /* 512    ||x_t||^2               */
#define WS_ZS   ((size_t)197632)   /* 512*256 d*Z                    */
#define WS_YS   ((size_t)328704)   /* 512*256 x + d*y                */
#define WS_GS   ((size_t)459776)   /* 4*512*256 g_1..g_4             */
#define WS_HS   ((size_t)984064)   /* 4*512   h_1..h_4               */
#define WS_ALS  ((size_t)986112)   /* 512*256 alpha_5                */
#define WS_BETS ((size_t)1117184)  /* 5*512*256 beta_5               */
#define WS_CT   ((size_t)1772544)  /* 512*5*256 c_0..c_4             */

__device__ __forceinline__ float wred_sum(float v) {
#pragma unroll
  for (int m = 1; m < 64; m <<= 1) v += __shfl_xor(v, m, 64);
  return v;
}
__device__ __forceinline__ float wred_min(float v) {
#pragma unroll
  for (int m = 1; m < 64; m <<= 1) v = fminf(v, __shfl_xor(v, m, 64));
  return v;
}
__device__ __forceinline__ float wred_max(float v) {
#pragma unroll
  for (int m = 1; m < 64; m <<= 1) v = fmaxf(v, __shfl_xor(v, m, 64));
  return v;
}
// sum over the 32 lanes of the same parity (h = lane&1) within a wave
__device__ __forceinline__ float psum32(float v) {
  v += __shfl_xor(v, 2, 64);
  v += __shfl_xor(v, 4, 64);
  v += __shfl_xor(v, 8, 64);
  v += __shfl_xor(v, 16, 64);
  v += __shfl_xor(v, 32, 64);
  return v;
}
__device__ __forceinline__ float rfl(float x) {
  return __builtin_bit_cast(float, __builtin_amdgcn_readfirstlane(__builtin_bit_cast(int, x)));
}

#define G_LIST(X) X(0) X(1) X(2) X(3) X(4) X(5) X(6) X(7) \
                  X(8) X(9) X(10) X(11) X(12) X(13) X(14) X(15) \
                  X(16) X(17) X(18) X(19) X(20) X(21) X(22) X(23) \
                  X(24) X(25) X(26) X(27) X(28) X(29) X(30) X(31)

// ---------------- K0a: G = B B^T, Gd ----------------
__global__ void k0_gram(const float* __restrict__ B, float* __restrict__ ws) {
  float* G = ws + WS_G;
  float* Gd = ws + WS_GD;
  __shared__ float bi[256];
  const int i = blockIdx.x, j = threadIdx.x;
  bi[j] = B[(size_t)i * 256 + j];
  __syncthreads();
  float a0 = 0.f, a1 = 0.f, a2 = 0.f, a3 = 0.f;
#pragma unroll
  for (int c = 0; c < 256; c += 4) {
    float4 b4 = *(const float4*)&B[(size_t)j * 256 + c];
    a0 = fmaf(bi[c + 0], b4.x, a0);
    a1 = fmaf(bi[c + 1], b4.y, a1);
    a2 = fmaf(bi[c + 2], b4.z, a2);
    a3 = fmaf(bi[c + 3], b4.w, a3);
  }
  float acc = (a0 + a1) + (a2 + a3);
  G[(size_t)i * 256 + j] = acc;
  if (i == j) Gd[i] = acc;
}

// ---------------- K0c: m0 ----------------
__global__ void k0_m0(const float* __restrict__ B, float* __restrict__ ws) {
  float* M0 = ws + WS_M0;
  const int d = threadIdx.x;
  float acc = 0.f;
  for (int i = 0; i < 256; ++i) acc += B[(size_t)i * 256 + d];
  M0[d] = acc * (1.0f / 256.0f);
}

// ---------------- K0b: BX[t] = B x_t, X2[t] ----------------
__global__ void k0_bx(const float* __restrict__ B, const float* __restrict__ embed,
                      const int* __restrict__ toks, float* __restrict__ ws) {
  float* BX = ws + WS_BX;
  float* X2 = ws + WS_X2;
  __shared__ float xs[256];
  __shared__ float red[4];
  const int t = blockIdx.x, i = threadIdx.x;
  const int lane = i & 63, wid = i >> 6;
  const int tok = toks[t];
  float xv = embed[(size_t)tok * 256 + i];
  xs[i] = xv;
  float p = wred_sum(xv * xv);
  if (lane == 0) red[wid] = p;
  __syncthreads();
  if (i == 0) X2[t] = red[0] + red[1] + red[2] + red[3];
  float a0 = 0.f, a1 = 0.f, a2 = 0.f, a3 = 0.f;
#pragma unroll
  for (int c = 0; c < 256; c += 4) {
    float4 b4 = *(const float4*)&B[(size_t)i * 256 + c];
    a0 = fmaf(xs[c + 0], b4.x, a0);
    a1 = fmaf(xs[c + 1], b4.y, a1);
    a2 = fmaf(xs[c + 2], b4.z, a2);
    a3 = fmaf(xs[c + 3], b4.w, a3);
  }
  BX[(size_t)t * 256 + i] = (a0 + a1) + (a2 + a3);
}

// ---------------- K1: sequential scan ----------------
// 512 threads: i = tid>>1 (row/dim), h = tid&1 (half of G-row).
// Half G-row = 32 NAMED float4 vars (128 VGPRs) -- macro-expanded straight-line
// uses so they cannot be demoted to scratch. amdgpu_waves_per_eu(2,2) pins the
// backend's occupancy target to 2 waves/EU (what one 8-wave workgroup gives
// anyway) -> 256-VGPR budget, ~190 needed, no spill.
// 2 barriers/round, 10/step; matvec input alpha_k written one segment ahead.
__global__ __launch_bounds__(512)
__attribute__((amdgpu_waves_per_eu(2, 2)))
void k1_seq(
    const float* __restrict__ embed, const int* __restrict__ toks,
    const float* __restrict__ mdbp, const float* __restrict__ sensp,
    float* __restrict__ ws) {
  const int tid = threadIdx.x;
  const int lane = tid & 63;
  const int i = tid >> 1, h = tid & 1;
  const float* G = ws + WS_G;
  const float* Gd = ws + WS_GD;
  const float* BX = ws + WS_BX;
  const float* X2 = ws + WS_X2;
  float* ZS = ws + WS_ZS;
  float* YS = ws + WS_YS;
  float* GS = ws + WS_GS;
  float* HS = ws + WS_HS;
  float* ALS = ws + WS_ALS;
  float* BETS = ws + WS_BETS;

  __shared__ __align__(16) float gcur[256];
  __shared__ float dresb[2][8];
  __shared__ float bbarb[2][8];

  // half G-row in 32 named float4 registers
  const float4* gp = (const float4*)(G + (size_t)i * 256 + (size_t)h * 128);
#define DECLG(J) float4 Gr##J = gp[J];
  G_LIST(DECLG)
#undef DECLG
  const float Gdi = Gd[i];
  const float mdb = rfl(mdbp[0]);
  const float sens = fabsf(rfl(sensp[0]));

  // q0 = G * (1/256) is constant across t
  float q0i;
  {
    float s = 0.f;
#define SUMG(J) s += (Gr##J.x + Gr##J.y) + (Gr##J.z + Gr##J.w);
    G_LIST(SUMG)
#undef SUMG
    s += __shfl_xor(s, 1, 64);
    q0i = s * (1.0f / 256.0f);
  }

  float x_c = embed[(size_t)toks[0] * 256 + i];
  float bx_c = BX[i];
  float x2_c = rfl(X2[0]);

  // zero all reduction buffers
  if (tid < 16) dresb[tid >> 3][tid & 7] = 0.f;
  else if (tid < 32) bbarb[(tid - 16) >> 3][tid & 7] = 0.f;
  __syncthreads();
  // preamble reductions: slot0 c00 = mean(q0) (h==0), slot1 mbx = mean(BX[0]) (h==1)
  {
    float v = h ? (bx_c * (1.0f / 256.0f)) : (q0i * (1.0f / 256.0f));
    v = psum32(v);
    if (lane == h) atomicAdd(&dresb[0][h], v);
  }
  __syncthreads();
  const float c00 = rfl(dresb[0][0]);
  float mbx = rfl(dresb[0][1]);

  float Zi = 0.f, yi = 0.f, wi = 0.f;
  float mm2 = 0.f, mw = 0.f, dotxm = 0.f;

  // t = 0 step scalars (mem == 0 -> nov = 1)
  float dec = 1.0f / (1.0f + expf(-(mdb - sens)));
  float od = 1.0f - dec;
  float ri = bx_c;
  float XM2 = x2_c;
  float mean_r = mbx;
  if (h == 0) ZS[i] = 0.f;
  else YS[i] = x_c;

  float gh[6], Ggh[6], hhv[6], bmat[5], xmm[5], alpha;
  gh[0] = 1.0f / 256.0f; Ggh[0] = q0i; hhv[0] = 0.f;
  // round-0 epilogue for t = 0
  {
    const float xmm0 = mean_r;
    const float tki = ETA * ri + KAPPA * q0i;
    const float CC00 = (ETA * ETA) * XM2 + 2.f * (ETA * KAPPA) * xmm0 +
                       (KAPPA * KAPPA) * c00;
    const float n2 = fmaxf(AA * AA * Gdi + 2.f * AA * tki + CC00, 0.f);
    const float inv = 1.0f / (sqrtf(n2) + 1e-10f);
    bmat[0] = inv; alpha = AA * inv; xmm[0] = xmm0;
  }
  if (h == 0) gcur[i] = alpha;
  {
    float bv = h ? 0.f : bmat[0];
    bv = psum32(bv);
    if (lane == 0) atomicAdd(&bbarb[1][0], bv);
  }
  __syncthreads();
  int pq = 1;

#pragma unroll 1
  for (int t = 0; t < SEQ; ++t) {
    const int tn = (t + 1 < SEQ) ? (t + 1) : t;
    const int tokn = toks[tn];
    const float x_n = embed[(size_t)tokn * 256 + i];
    const float bx_n = BX[(size_t)tn * 256 + i];
    const float x2_n = rfl(X2[tn]);
    float q5sav = 0.f;

#pragma unroll
    for (int k = 1; k <= 5; ++k) {
      // ===================== A_k =====================
      if (tid < 8) dresb[1 - pq][tid] = 0.f;
      else if (tid < 16) bbarb[1 - pq][tid - 8] = 0.f;
      // matvec M[i] = sum_j G[i][j] * alpha_k[j]  (half-row per parity)
      float4 av = {0.f, 0.f, 0.f, 0.f};
      const float4* gc4 = (const float4*)&gcur[h * 128];
#define MVG(J) { const float4 g4 = gc4[J]; \
      av.x = fmaf(Gr##J.x, g4.x, av.x); av.y = fmaf(Gr##J.y, g4.y, av.y); \
      av.z = fmaf(Gr##J.z, g4.z, av.z); av.w = fmaf(Gr##J.w, g4.w, av.w); }
      G_LIST(MVG)
#undef MVG
      float M = (av.x + av.y) + (av.z + av.w);
      M += __shfl_xor(M, 1, 64);
      // g_k, Gg_k, h_k from bbar history
      float hk = 0.f, gk = alpha * (1.0f / 256.0f), Ggk = M * (1.0f / 256.0f);
#pragma unroll
      for (int l = 0; l < 5; ++l)
        if (l < k) {
          const float bb = rfl(bbarb[pq][l]) * (1.0f / 256.0f);
          hk += bb * (ETA + KAPPA * hhv[l]);
          gk = fmaf(KAPPA * bb, gh[l], gk);
          Ggk = fmaf(KAPPA * bb, Ggh[l], Ggk);
        }
      const float qk = Ggk + hk * ri;
      gh[k] = gk; Ggh[k] = Ggk; hhv[k] = hk;
      if (k <= 4) {
        if (h == 1) GS[(size_t)(k - 1) * (SEQ * 256) + (size_t)t * 256 + i] = gk;
        if (tid == 0) HS[(size_t)(k - 1) * SEQ + t] = hk;
      }
      // reduction vectors
      float vv[8];
      if (k < 5) {
#pragma unroll
        for (int l = 0; l < 8; ++l) {
          if (l <= k) vv[l] = gk * (Ggh[l] + hhv[l] * ri);
          else if (l == k + 1) vv[l] = ri * gk;
          else vv[l] = 0.f;
        }
      } else {
        q5sav = qk;
        vv[0] = gk * qk;                  // <g5,q5>
        vv[1] = ri * gk;                  // <r,g5>
        vv[2] = wi * gk;                  // <w,g5>
        vv[3] = qk * (1.0f / 256.0f);     // mean(q5)
        vv[4] = bx_n * Zi + x_n * yi;     // <x_n, mem_old>
        vv[5] = bx_n * gk;                // <bx_n, g5>
        vv[6] = x_n * x_c;                // <x_n, x_c>
        vv[7] = bx_n * (1.0f / 256.0f);   // mean(bx_n)
      }
      // parity h handles slots h*4 + {0..3}
      const int nv = (k < 5) ? (k + 2) : 8;
      const int ulim = (k < 5) ? (k + 2) : 4;   // max u needed by either parity
      float red4[4] = {0.f, 0.f, 0.f, 0.f};
#pragma unroll
      for (int u = 0; u < 4; ++u)
        if (u < ulim) red4[u] = psum32(h ? vv[4 + u] : vv[u]);
      if (lane == h) {
#pragma unroll
        for (int u = 0; u < 4; ++u) {
          const int sl = h * 4 + u;
          if (sl < nv) atomicAdd(&dresb[pq][sl], red4[u]);
        }
      }
      __syncthreads();

      // ===================== B_k =====================
      if (k < 5) {
        float dres[7];
#pragma unroll
        for (int l = 0; l < 7; ++l)
          if (l <= k + 1) dres[l] = rfl(dresb[pq][l]);
        const float xmmk = dres[k + 1] + hk * XM2;
        const float tki = ETA * ri + KAPPA * qk;
        float sc = alpha * tki;
#pragma unroll
        for (int jj = 0; jj < 4; ++jj)
          if (jj < k) {
            const float MMjk = dres[jj] + hk * xmm[jj];
            const float CCjk = (ETA * ETA) * XM2 + (ETA * KAPPA) * (xmm[jj] + xmmk) +
                               (KAPPA * KAPPA) * MMjk;
            sc = fmaf(bmat[jj], CCjk, sc);
          }
        const float MMkk = dres[k] + hk * xmmk;
        const float CCkk = (ETA * ETA) * XM2 + 2.f * (ETA * KAPPA) * xmmk +
                           (KAPPA * KAPPA) * MMkk;
        const float n2 = fmaxf(AA * AA + 2.f * AA * sc + CCkk, 0.f);
        const float inv = 1.0f / (sqrtf(n2) + 1e-10f);
#pragma unroll
        for (int jj = 0; jj < 4; ++jj)
          if (jj < k) bmat[jj] *= AA * inv;
        bmat[k] = inv;
        alpha *= AA * inv;
        xmm[k] = xmmk;
        if (k == 4) {
          if (h == 1) {
            ALS[(size_t)t * 256 + i] = alpha;
            BETS[(size_t)1 * (SEQ * 256) + (size_t)t * 256 + i] = bmat[1];
            BETS[(size_t)3 * (SEQ * 256) + (size_t)t * 256 + i] = bmat[3];
          } else {
            BETS[(size_t)0 * (SEQ * 256) + (size_t)t * 256 + i] = bmat[0];
            BETS[(size_t)2 * (SEQ * 256) + (size_t)t * 256 + i] = bmat[2];
            BETS[(size_t)4 * (SEQ * 256) + (size_t)t * 256 + i] = bmat[4];
          }
        }
        if (h == 0) gcur[i] = alpha;  // alpha_{k+1}
        // bbar partial sums: h0 -> slots 0,2,4 ; h1 -> slots 1,3
        float rb0 = h ? bmat[1] : bmat[0];
        float rb1 = h ? ((k >= 3) ? bmat[3] : 0.f) : ((k >= 2) ? bmat[2] : 0.f);
        float rb2 = h ? 0.f : ((k >= 4) ? bmat[4] : 0.f);
        rb0 = psum32(rb0);
        if (k >= 2) rb1 = psum32(rb1);
        if (k >= 4) rb2 = psum32(rb2);
        if (lane == h) {
          atomicAdd(&bbarb[1 - pq][h], rb0);
          if (2 + h <= k) atomicAdd(&bbarb[1 - pq][2 + h], rb1);
          if (4 + h <= k) atomicAdd(&bbarb[1 - pq][4 + h], rb2);
        }
        __syncthreads();
        pq ^= 1;
      } else {
        // B_5: memory update + next-step scalars + next round-0
        float dr[8];
#pragma unroll
        for (int l = 0; l < 8; ++l) dr[l] = rfl(dresb[pq][l]);
        const float h5 = hhv[5];
        const float g5 = gh[5];
        const float q5 = q5sav;
        const float xmm5 = dr[1] + h5 * XM2;
        const float m52 = dr[0] + h5 * xmm5;
        const float cmm5 = dr[2] + h5 * (dotxm + dec * mm2);
        const float lamc = dec * (1.0f + od * h5);
        Zi = lamc * Zi + od * g5;
        yi = lamc * yi + od * h5 * x_c;
        wi = dec * wi + od * q5;
        mm2 = fmaxf(dec * dec * mm2 + 2.f * dec * od * cmm5 + od * od * m52, 0.f);
        mw = dec * mw + od * dr[3];
        dotxm = lamc * dr[4] + od * (dr[5] + h5 * dr[6]);
        mbx = dr[7];
        x_c = x_n; bx_c = bx_n; x2_c = x2_n;
        // next-step scalars
        const float memnorm = sqrtf(mm2) + 1e-10f;
        const float xnorm = sqrtf(x2_c) + 1e-10f;
        const float nov = (memnorm > 1e-8f) ? (1.0f - dotxm / (xnorm * memnorm)) : 1.0f;
        dec = 1.0f / (1.0f + expf(-(mdb - sens * nov)));
        od = 1.0f - dec;
        ri = bx_c + dec * wi;
        XM2 = x2_c + 2.f * dec * dotxm + dec * dec * mm2;
        mean_r = mbx + dec * mw;
        if (t + 1 < SEQ) {
          if (h == 0) ZS[(size_t)(t + 1) * 256 + i] = dec * Zi;
          else YS[(size_t)(t + 1) * 256 + i] = x_c + dec * yi;
        }
        // round-0 epilogue for next step
        const float xmm0 = mean_r;
        const float tki = ETA * ri + KAPPA * q0i;
        const float CC00 = (ETA * ETA) * XM2 + 2.f * (ETA * KAPPA) * xmm0 +
                           (KAPPA * KAPPA) * c00;
        const float n2 = fmaxf(AA * AA * Gdi + 2.f * AA * tki + CC00, 0.f);
        const float inv = 1.0f / (sqrtf(n2) + 1e-10f);
        bmat[0] = inv; alpha = AA * inv; xmm[0] = xmm0;
        if (h == 0) gcur[i] = alpha;  // alpha_1
        float bv = h ? 0.f : bmat[0];
        bv = psum32(bv);
        if (lane == 0) atomicAdd(&bbarb[1 - pq][0], bv);
        __syncthreads();
        pq ^= 1;
      }
    }
  }
}

// ---------------- K15: materialize xm and c_0..c_4 per step ----------------
__global__ void k15_cvec(const float* __restrict__ B, float* __restrict__ ws) {
  const float* ZS = ws + WS_ZS;
  const float* YS = ws + WS_YS;
  const float* GS = ws + WS_GS;
  const float* HS = ws + WS_HS;
  const float* M0 = ws + WS_M0;
  float* CT = ws + WS_CT;
  const int t = blockIdx.x, d = threadIdx.x;
  __shared__ float zs[256], g1[256], g2[256], g3[256], g4[256];
  zs[d] = ZS[(size_t)t * 256 + d];
  g1[d] = GS[0 * (SEQ * 256) + (size_t)t * 256 + d];
  g2[d] = GS[1 * (SEQ * 256) + (size_t)t * 256 + d];
  g3[d] = GS[2 * (SEQ * 256) + (size_t)t * 256 + d];
  g4[d] = GS[3 * (SEQ * 256) + (size_t)t * 256 + d];
  __syncthreads();
  float xa = 0.f, b1 = 0.f, b2 = 0.f, b3 = 0.f, b4 = 0.f;
  for (int ii = 0; ii < 256; ++ii) {
    const float Bv = B[(size_t)ii * 256 + d];
    xa = fmaf(zs[ii], Bv, xa);
    b1 = fmaf(g1[ii], Bv, b1);
    b2 = fmaf(g2[ii], Bv, b2);
    b3 = fmaf(g3[ii], Bv, b3);
    b4 = fmaf(g4[ii], Bv, b4);
  }
  const float xm = YS[(size_t)t * 256 + d] + xa;
  float* ctt = CT + (size_t)t * 1280;
  ctt[0 * 256 + d] = ETA * xm + KAPPA * M0[d];
  const float h1 = HS[0 * SEQ + t], h2 = HS[1 * SEQ + t];
  const float h3 = HS[2 * SEQ + t], h4 = HS[3 * SEQ + t];
  ctt[1 * 256 + d] = (ETA + KAPPA * h1) * xm + KAPPA * b1;
  ctt[2 * 256 + d] = (ETA + KAPPA * h2) * xm + KAPPA * b2;
  ctt[3 * 256 + d] = (ETA + KAPPA * h3) * xm + KAPPA * b3;
  ctt[4 * 256 + d] = (ETA + KAPPA * h4) * xm + KAPPA * b4;
}

// ---------------- K2: per-step rho -> eigenvalues ----------------
__global__ __launch_bounds__(1024, 4) void k2_eig(
    const float* __restrict__ B, const float* __restrict__ ws,
    float* __restrict__ out) {
  const int t = blockIdx.x;
  const int tid = threadIdx.x;
  const int lane = tid & 63, wid = tid >> 6;
  const float* CT = ws + WS_CT + (size_t)t * 1280;
  const float* ALS = ws + WS_ALS + (size_t)t * 256;
  const float* BETS = ws + WS_BETS;

  __shared__ __align__(16) unsigned char bigbuf[135168];  // sT fp16 [256][264] / packed rho fp32
  _Float16* sT = (_Float16*)bigbuf;
  float* pk = (float*)bigbuf;
  __shared__ __align__(16) float ct[1280];
  __shared__ float vx[256], pv[256], qv[256];
  __shared__ float dd[256], ee[256], e2[256], lamv[256];
  __shared__ float red[16];

  for (int idx = tid; idx < 1280; idx += 1024) ct[idx] = CT[idx];
  __syncthreads();

  // --- regenerate s5 rows, store transposed fp16 ---
  {
    const int r = tid >> 2, q = tid & 3;
    const float al = ALS[r];
    const float be0 = BETS[(size_t)0 * (SEQ * 256) + (size_t)t * 256 + r];
    const float be1 = BETS[(size_t)1 * (SEQ * 256) + (size_t)t * 256 + r];
    const float be2 = BETS[(size_t)2 * (SEQ * 256) + (size_t)t * 256 + r];
    const float be3 = BETS[(size_t)3 * (SEQ * 256) + (size_t)t * 256 + r];
    const float be4 = BETS[(size_t)4 * (SEQ * 256) + (size_t)t * 256 + r];
#pragma unroll
    for (int j4 = 0; j4 < 16; ++j4) {
      const int d0 = q * 64 + j4 * 4;
      const float4 Bv = *(const float4*)&B[(size_t)r * 256 + d0];
      const float4 c0 = *(const float4*)&ct[0 * 256 + d0];
      const float4 c1 = *(const float4*)&ct[1 * 256 + d0];
      const float4 c2 = *(const float4*)&ct[2 * 256 + d0];
      const float4 c3 = *(const float4*)&ct[3 * 256 + d0];
      const float4 c4 = *(const float4*)&ct[4 * 256 + d0];
      const float s0 = al * Bv.x + be0 * c0.x + be1 * c1.x + be2 * c2.x + be3 * c3.x + be4 * c4.x;
      const float s1 = al * Bv.y + be0 * c0.y + be1 * c1.y + be2 * c2.y + be3 * c3.y + be4 * c4.y;
      const float s2 = al * Bv.z + be0 * c0.z + be1 * c1.z + be2 * c2.z + be3 * c3.z + be4 * c4.z;
      const float s3 = al * Bv.w + be0 * c0.w + be1 * c1.w + be2 * c2.w + be3 * c3.w + be4 * c4.w;
      sT[(size_t)(d0 + 0) * 264 + r] = (_Float16)s0;
      sT[(size_t)(d0 + 1) * 264 + r] = (_Float16)s1;
      sT[(size_t)(d0 + 2) * 264 + r] = (_Float16)s2;
      sT[(size_t)(d0 + 3) * 264 + r] = (_Float16)s3;
    }
  }
  __syncthreads();

  // --- rho = sT * sT^T / 256 via MFMA f16 (4x4 tiles of 16x16 per wave) ---
  f32x4 acc[4][4];
#pragma unroll
  for (int ti = 0; ti < 4; ++ti)
#pragma unroll
    for (int tj = 0; tj < 4; ++tj) {
      f32x4 z = {0.f, 0.f, 0.f, 0.f};
      acc[ti][tj] = z;
    }
  {
    const int Ib = (wid >> 2) * 4, Jb = (wid & 3) * 4;
    const int mr = lane & 15, kg = lane >> 4;
#pragma unroll 1
    for (int kb = 0; kb < 8; ++kb) {
      const int ko = kb * 32 + kg * 8;
      f16x8 aF[4], bF[4];
#pragma unroll
      for (int ti = 0; ti < 4; ++ti)
        aF[ti] = *(const f16x8*)&sT[(size_t)((Ib + ti) * 16 + mr) * 264 + ko];
#pragma unroll
      for (int tj = 0; tj < 4; ++tj)
        bF[tj] = *(const f16x8*)&sT[(size_t)((Jb + tj) * 16 + mr) * 264 + ko];
#pragma unroll
      for (int ti = 0; ti < 4; ++ti)
#pragma unroll
        for (int tj = 0; tj < 4; ++tj)
          acc[ti][tj] = __builtin_amdgcn_mfma_f32_16x16x32_f16(aF[ti], bF[tj], acc[ti][tj], 0, 0, 0);
    }
  }
  __syncthreads();
  {
    const int Ib = (wid >> 2) * 4, Jb = (wid & 3) * 4;
    const int cn = lane & 15, rg = lane >> 4;
#pragma unroll
    for (int ti = 0; ti < 4; ++ti)
#pragma unroll
      for (int tj = 0; tj < 4; ++tj) {
        const int C = (Jb + tj) * 16 + cn;
        const int Rb = (Ib + ti) * 16 + rg * 4;
#pragma unroll
        for (int rr = 0; rr < 4; ++rr) {
          const int R = Rb + rr;
          if (R >= C) pk[R * (R + 1) / 2 + C] = acc[ti][tj][rr] * (1.0f / 256.0f);
        }
      }
  }
  __syncthreads();

  // --- Householder tridiagonalization on packed lower fp32 ---
#pragma unroll 1
  for (int j = 0; j < 254; ++j) {
    const int m = 255 - j;
    const float x0 = pk[(j + 1) * (j + 2) / 2 + j];
    float ps = 0.f;
    if (tid < m) {
      const int gr = j + 1 + tid;
      const float xv_ = pk[gr * (gr + 1) / 2 + j];
      vx[tid] = xv_;
      ps = xv_ * xv_;
    }
    ps = wred_sum(ps);
    if (lane == 0) red[wid] = ps;
    __syncthreads();  // T1
    float sig2 = 0.f;
#pragma unroll
    for (int w = 0; w < 16; ++w) sig2 += red[w];
    const float sig = sqrtf(sig2);
    const float sg = (x0 >= 0.f) ? 1.f : -1.f;
    const bool live = (sig2 > 1e-26f);
    const float beta = live ? (1.0f / (sig * (sig + fabsf(x0)))) : 0.f;
    const float v0 = live ? (x0 + sg * sig) : 0.f;
    if (tid == 0) {
      dd[j] = pk[j * (j + 1) / 2 + j];
      ee[j] = live ? (-sg * sig) : x0;
      vx[0] = v0;
    }
    __syncthreads();  // T2
    {
      const int ri_ = tid >> 2, qd = tid & 3;
      float acc2 = 0.f;
      if (ri_ < m) {
        const int gr = j + 1 + ri_;
        const int c0 = (m * qd) >> 2, c1 = (m * (qd + 1)) >> 2;
        const int rowbase = gr * (gr + 1) / 2 + (j + 1);
        const int clend = min(c1, ri_ + 1);
        for (int c = c0; c < clend; ++c) acc2 = fmaf(pk[rowbase + c], vx[c], acc2);
        const int cu = max(c0, ri_ + 1);
        if (cu < c1) {
          int gc = j + 1 + cu;
          int ub = gc * (gc + 1) / 2 + gr;
          int stp = gc + 1;
          for (int c = cu; c < c1; ++c) { acc2 = fmaf(pk[ub], vx[c], acc2); ub += stp; ++stp; }
        }
      }
      acc2 += __shfl_xor(acc2, 1, 64);
      acc2 += __shfl_xor(acc2, 2, 64);
      float vpp = 0.f;
      if ((tid & 3) == 0 && (tid >> 2) < m) { pv[tid >> 2] = acc2; vpp = acc2 * vx[tid >> 2]; }
      vpp = wred_sum(vpp);
      if (lane == 0) red[wid] = vpp;
    }
    __syncthreads();  // T3
    float vtp = 0.f;
#pragma unroll
    for (int w = 0; w < 16; ++w) vtp += red[w];
    const float gamma = 0.5f * beta * beta * vtp;
    if (tid < m) qv[tid] = beta * pv[tid] - gamma * vx[tid];
    __syncthreads();  // T4
    {
      const int Q = tid >> 2, qd = tid & 3;
      const int i2 = m - 1 - Q;
      if (Q <= i2 && Q < m) {
        {
          const int gr = j + 1 + Q;
          const int rb = gr * (gr + 1) / 2 + (j + 1);
          const float vi = vx[Q], qi = qv[Q];
          const int cs = (qd * (Q + 1)) >> 2, ce = ((qd + 1) * (Q + 1)) >> 2;
          for (int c = cs; c < ce; ++c) pk[rb + c] -= vi * qv[c] + qi * vx[c];
        }
        if (i2 > Q) {
          const int gr = j + 1 + i2;
          const int rb = gr * (gr + 1) / 2 + (j + 1);
          const float vi = vx[i2], qi = qv[i2];
          const int cs = (qd * (i2 + 1)) >> 2, ce = ((qd + 1) * (i2 + 1)) >> 2;
          for (int c = cs; c < ce; ++c) pk[rb + c] -= vi * qv[c] + qi * vx[c];
        }
      }
    }
    __syncthreads();  // T5
  }
  if (tid == 0) {
    dd[254] = pk[254 * 255 / 2 + 254];
    dd[255] = pk[255 * 256 / 2 + 255];
    ee[254] = pk[255 * 256 / 2 + 254];
    ee[255] = 0.f;
  }
  __syncthreads();
  if (tid < 256) e2[tid] = ee[tid] * ee[tid];
  __syncthreads();
  float glo = 1e30f, ghi = -1e30f;
  if (tid < 256) {
    const float rad = fabsf(ee[tid]) + ((tid > 0) ? fabsf(ee[tid - 1]) : 0.f);
    glo = dd[tid] - rad;
    ghi = dd[tid] + rad;
  }
  {
    float v = wred_min(glo);
    if (lane == 0) red[wid] = v;
    __syncthreads();
    float lo0 = 1e30f;
#pragma unroll
    for (int w = 0; w < 16; ++w) lo0 = fminf(lo0, red[w]);
    __syncthreads();
    v = wred_max(ghi);
    if (lane == 0) red[wid] = v;
    __syncthreads();
    float hi0 = -1e30f;
#pragma unroll
    for (int w = 0; w < 16; ++w) hi0 = fmaxf(hi0, red[w]);
    lo0 -= 1e-3f + 1e-3f * fabsf(lo0);
    hi0 += 1e-3f + 1e-3f * fabsf(hi0);
    if (tid < 256) {
      float lo = lo0, hi = hi0;
      for (int it = 0; it < 21; ++it) {
        const float x = 0.5f * (lo + hi);
        int cnt = 0;
        float qq = dd[0] - x;
        cnt += (qq < 0.f);
        for (int ii = 1; ii < 256; ++ii) {
          float dn = qq;
          if (fabsf(dn) < 1e-25f) dn = (dn < 0.f) ? -1e-25f : 1e-25f;
          qq = (dd[ii] - x) - e2[ii - 1] * __builtin_amdgcn_rcpf(dn);
          cnt += (qq < 0.f);
        }
        if (cnt >= tid + 1) hi = x; else lo = x;
      }
      lamv[tid] = fmaxf(0.5f * (lo + hi), 0.f);
    }
  }
  __syncthreads();
  float sv = (tid < 256) ? lamv[tid] : 0.f;
  sv = wred_sum(sv);
  if (lane == 0) red[wid] = sv;
  __syncthreads();
  float S = 0.f;
#pragma unroll
  for (int w = 0; w < 16; ++w) S += red[w];
  if (tid < 256) out[(size_t)t * 256 + tid] = lamv[tid] / (S + 1e-10f);
}

extern "C" void kernel_launch(void* const* d_in, const int* in_sizes, int n_in,
                              void* d_out, int out_size, void* d_ws, size_t ws_size,
                              hipStream_t stream) {
  const float* embed = (const float*)d_in[0];
  const float* B = (const float*)d_in[1];
  const float* mdb = (const float*)d_in[2];
  const float* sens = (const float*)d_in[3];
  const int* toks = (const int*)d_in[4];
  float* out = (float*)d_out;
  float* ws = (float*)d_ws;

  k0_gram<<<dim3(256), dim3(256), 0, stream>>>(B, ws);
  k0_m0<<<dim3(1), dim3(256), 0, stream>>>(B, ws);
  k0_bx<<<dim3(SEQ), dim3(256), 0, stream>>>(B, embed, toks, ws);
  k1_seq<<<dim3(1), dim3(512), 0, stream>>>(embed, toks, mdb, sens, ws);
  k15_cvec<<<dim3(SEQ), dim3(256), 0, stream>>>(B, ws);
  k2_eig<<<dim3(SEQ), dim3(1024), 0, stream>>>(B, ws, out);
}